// Round 4
// baseline (323.842 us; speedup 1.0000x reference)
//
#include <hip/hip_runtime.h>

#define B_  64
#define T_  1000
#define DV_ 512
#define DQ_ 1024
#define U_  128
#define F_  32
#define KS_ 31
#define P_  16     // context partial chunks per batch
#define CT_ 63     // t per chunk (last chunk 55)

typedef __attribute__((ext_vector_type(8))) short short8;
typedef __attribute__((ext_vector_type(4))) float f32x4;

// round-to-nearest-even f32 -> bf16 (bit trick), packed pair
__device__ __forceinline__ unsigned pk2(float a, float b) {
    union { float f; unsigned u; } x, y;
    x.f = a; y.f = b;
    unsigned ra = (x.u + 0x7FFFu + ((x.u >> 16) & 1u)) >> 16;
    unsigned rb = (y.u + 0x7FFFu + ((y.u >> 16) & 1u)) >> 16;
    return (ra & 0xFFFFu) | (rb << 16);
}

__device__ __forceinline__ float fast_tanh(float x) {
    return 1.0f - 2.0f / (__expf(2.0f * x) + 1.0f);
}

// pack two float4 (8 consecutive k) into bf16 short8
__device__ __forceinline__ short8 pk8(float4 f0, float4 f1) {
    int4 q;
    q.x = pk2(f0.x, f0.y); q.y = pk2(f0.z, f0.w);
    q.z = pk2(f1.x, f1.y); q.w = pk2(f1.z, f1.w);
    return *(short8*)&q;
}

// async global->LDS DMA, 16B per lane; lptr must be wave-uniform
__device__ __forceinline__ void gload_lds16(const void* g, void* l) {
    __builtin_amdgcn_global_load_lds(
        (const __attribute__((address_space(1))) unsigned*)g,
        (__attribute__((address_space(3))) unsigned*)l, 16, 0, 0);
}

// ---------------------------------------------------------------------------
// Merged: prep (repack Wm/Wl to bf16 B-frag layout) + qb (query proj).
// Blocks 0..8: prep. Blocks 9..72: qb for b = blk-9.
// ---------------------------------------------------------------------------
__global__ __launch_bounds__(1024) void prep_qb_kernel(
    const float* __restrict__ Wm, const float* __restrict__ Wl,
    const float* __restrict__ query, const float* __restrict__ Wq,
    const float* __restrict__ bq, const float* __restrict__ bm,
    short* __restrict__ WmX, short* __restrict__ WlX, float* __restrict__ qb)
{
    __shared__ float sh[DQ_ + 8 * U_];
    int blk = blockIdx.x, tid = threadIdx.x;
    if (blk < 9) {
        int g = blk * 1024 + tid;
        if (g < 8192) {
            int kc = g >> 9, e = g & 511;
            int n = e >> 2, q = e & 3;
            int kb = kc * 32 + q * 8;
            int4 p;
            p.x = pk2(Wm[(kb + 0) * U_ + n], Wm[(kb + 1) * U_ + n]);
            p.y = pk2(Wm[(kb + 2) * U_ + n], Wm[(kb + 3) * U_ + n]);
            p.z = pk2(Wm[(kb + 4) * U_ + n], Wm[(kb + 5) * U_ + n]);
            p.w = pk2(Wm[(kb + 6) * U_ + n], Wm[(kb + 7) * U_ + n]);
            ((int4*)WmX)[g] = p;
        } else if (g < 8704) {
            int e = g - 8192;
            int n = e >> 2, q = e & 3;
            int kb = q * 8;
            int4 p;
            p.x = pk2(Wl[(kb + 0) * U_ + n], Wl[(kb + 1) * U_ + n]);
            p.y = pk2(Wl[(kb + 2) * U_ + n], Wl[(kb + 3) * U_ + n]);
            p.z = pk2(Wl[(kb + 4) * U_ + n], Wl[(kb + 5) * U_ + n]);
            p.w = pk2(Wl[(kb + 6) * U_ + n], Wl[(kb + 7) * U_ + n]);
            ((int4*)WlX)[e] = p;
        }
    } else {
        float* qs = sh;
        float* red = sh + DQ_;
        int b = blk - 9;
        qs[tid] = query[b * DQ_ + tid];
        __syncthreads();
        int u = tid & 127, p = tid >> 7;
        float a = 0.f;
        const float* wp = Wq + (size_t)p * 128 * U_ + u;
        const float* qp = qs + p * 128;
#pragma unroll 8
        for (int k = 0; k < 128; ++k) a += qp[k] * wp[(size_t)k * U_];
        red[p * U_ + u] = a;
        __syncthreads();
        if (tid < U_) {
            float s = bq[tid] + bm[tid];
#pragma unroll
            for (int pp = 0; pp < 8; ++pp) s += red[pp * U_ + tid];
            qb[b * U_ + tid] = s;
        }
    }
}

// ---------------------------------------------------------------------------
// scores[r], r=b*T+t: tanh(values@Wm + qb + tanh(conv(prev)@Wl)) @ Wv + bv
// M=64 rows/block (1000 blocks). A staged fp32 via global_load_lds (16B),
// double-buffered 64x64 tiles, 1 barrier/step; 16B-unit XOR swizzle folded
// into DMA src addrs. B direct from L2-hot repacked WmX (kc prefetch regs).
// ---------------------------------------------------------------------------
__global__ __launch_bounds__(256, 3) void score_kernel(
    const float* __restrict__ values, const float* __restrict__ prev,
    const float* __restrict__ Wc, const float* __restrict__ Wv,
    const float* __restrict__ bv, const short* __restrict__ WmX,
    const short* __restrict__ WlX, const float* __restrict__ qb,
    float* __restrict__ scores)
{
    __shared__ float As[2][64 * 64];   // [buf][row*64 + f], 256B rows, unit-swizzled
    __shared__ short AsL[64 * 32];     // conv result, bf16 A-frag layout + XOR swizzle
    __shared__ float WcS[KS_ * F_];
    __shared__ float qbS[2 * U_];
    __shared__ float WvS[U_];

    const int tid = threadIdx.x;
    const int r0 = blockIdx.x * 64;
    const int b0 = r0 / T_;
    const int b1 = (r0 + 63) / T_;

    const int wv = tid >> 6, lane = tid & 63;
    const int quad = lane >> 4, m15 = lane & 15;
    const int esw = (m15 & 3) << 1;            // frag-read unit swizzle
    const int lrow = lane >> 4;                // staging: row-in-group-of-4
    const int lunit = (lane & 15) ^ (lrow << 1); // staging: swizzled src unit

    const int4* bW  = (const int4*)WmX + m15 * 4 + quad;
    const int4* blW = (const int4*)WlX + m15 * 4 + quad;

    // ---- stage lambda: DMA 64 rows x 64 floats window [k0, k0+64) into buf
    auto stage = [&](int buf, int k0) {
#pragma unroll
        for (int j = 0; j < 4; ++j) {
            const float* src = values + (size_t)(r0 + wv * 16 + j * 4 + lrow) * DV_
                               + k0 + lunit * 4;
            gload_lds16(src, &As[buf][(wv * 16 + j * 4) * 64]);
        }
    };

    // initial staging (step 0) + first B prefetch — in flight across conv
    stage(0, 0);
    int4 bfA[8], bfB[8];
#pragma unroll
    for (int c = 0; c < 8; ++c) bfA[c] = bW[c * 64];

    for (int i = tid; i < KS_ * F_; i += 256) WcS[i] = Wc[i];
    if (tid < U_) WvS[tid] = Wv[tid];
    {
        int bb = (tid < U_) ? b0 : b1;
        qbS[tid] = qb[bb * U_ + (tid & (U_ - 1))];
    }
    __syncthreads();   // WcS/qbS/WvS ready (DMA drained too — harmless, early)

    // location conv: loc_pre[i,f] = sum_k prev[b, t+k-15]*Wc[k,f] (SAME pad)
    {
        int i = tid & 63, fg = tid >> 6;
        int r = r0 + i;
        int b = r / T_;
        int t = r - b * T_;
        const float* pv = prev + b * T_;
        float a8[8] = {};
#pragma unroll
        for (int k = 0; k < KS_; ++k) {
            int tt = t + k - 15;
            float p = ((unsigned)tt < (unsigned)T_) ? pv[tt] : 0.f;
#pragma unroll
            for (int j = 0; j < 8; ++j) a8[j] += p * WcS[k * F_ + fg * 8 + j];
        }
        int4 pq;
        pq.x = pk2(a8[0], a8[1]); pq.y = pk2(a8[2], a8[3]);
        pq.z = pk2(a8[4], a8[5]); pq.w = pk2(a8[6], a8[7]);
        ((int4*)AsL)[i * 4 + (fg ^ ((i >> 1) & 3))] = pq;
    }
    __syncthreads();

    // loc GEMM (K=32) -> acc init = qb + tanh(loc)
    const int row = wv * 16 + m15;
    f32x4 acc[8] = {};
    {
        short8 afl = ((const short8*)AsL)[row * 4 + (quad ^ ((row >> 1) & 3))];
#pragma unroll
        for (int c = 0; c < 8; ++c) {
            int4 bl = blW[c * 64];
            acc[c] = __builtin_amdgcn_mfma_f32_16x16x32_bf16(afl, *(short8*)&bl, acc[c], 0, 0, 0);
        }
        int qoff[4];
#pragma unroll
        for (int v = 0; v < 4; ++v) {
            int r = r0 + wv * 16 + quad * 4 + v;
            qoff[v] = ((r / T_) == b0) ? 0 : U_;
        }
#pragma unroll
        for (int c = 0; c < 8; ++c) {
            int col = c * 16 + m15;
#pragma unroll
            for (int v = 0; v < 4; ++v)
                acc[c][v] = qbS[qoff[v] + col] + fast_tanh(acc[c][v]);
        }
    }
    __syncthreads();   // AsL reads done; buf0 DMA complete

    // main loop: 8 steps x (BK=64 = 2 kc); one barrier per step
#pragma unroll
    for (int s = 0; s < 8; ++s) {
        if (s + 1 < 8) stage((s + 1) & 1, (s + 1) * 64);
#pragma unroll
        for (int c = 0; c < 8; ++c) bfB[c] = bW[(2 * s + 1) * 512 + c * 64];

        const float4* ap = (const float4*)&As[s & 1][row * 64];
        // kc = 0
        {
            int u0 = (2 * quad) ^ esw;
            float4 f0 = ap[u0], f1 = ap[u0 + 1];
            short8 af = pk8(f0, f1);
#pragma unroll
            for (int c = 0; c < 8; ++c)
                acc[c] = __builtin_amdgcn_mfma_f32_16x16x32_bf16(af, *(short8*)&bfB[0] == *(short8*)&bfB[0] ? *(short8*)&bfA[c] : *(short8*)&bfA[c], acc[c], 0, 0, 0);
        }
        int4 bfN[8];
        if (s + 1 < 8) {
#pragma unroll
            for (int c = 0; c < 8; ++c) bfN[c] = bW[(2 * s + 2) * 512 + c * 64];
        }
        // kc = 1
        {
            int u0 = (2 * (4 + quad)) ^ esw;
            float4 f0 = ap[u0], f1 = ap[u0 + 1];
            short8 af = pk8(f0, f1);
#pragma unroll
            for (int c = 0; c < 8; ++c)
                acc[c] = __builtin_amdgcn_mfma_f32_16x16x32_bf16(af, *(short8*)&bfB[c], acc[c], 0, 0, 0);
        }
#pragma unroll
        for (int c = 0; c < 8; ++c) bfA[c] = bfN[c];
        __syncthreads();
    }

    // epilogue: score = sum_col tanh(acc)*Wv[col] + bv
    float psum[4] = {0.f, 0.f, 0.f, 0.f};
#pragma unroll
    for (int c = 0; c < 8; ++c) {
        int col = c * 16 + m15;
        float wvv = WvS[col];
#pragma unroll
        for (int v = 0; v < 4; ++v)
            psum[v] += fast_tanh(acc[c][v]) * wvv;
    }
#pragma unroll
    for (int off = 1; off < 16; off <<= 1) {
#pragma unroll
        for (int v = 0; v < 4; ++v) psum[v] += __shfl_xor(psum[v], off);
    }
    if (m15 == 0) {
        float bvv = bv[0];
#pragma unroll
        for (int v = 0; v < 4; ++v)
            scores[r0 + wv * 16 + quad * 4 + v] = psum[v] + bvv;
    }
}

// ---------------------------------------------------------------------------
// fused softmax + context partial. grid (64, 16). Each block recomputes the
// softmax stats from scores (L2-hot, 4KB), writes its attw t-slice, and
// accumulates partial context over its 63-t chunk.
// ---------------------------------------------------------------------------
__global__ __launch_bounds__(256) void ctxsm_kernel(
    const float* __restrict__ scores, const float* __restrict__ values,
    float* __restrict__ attw, float* __restrict__ part)
{
    __shared__ float sS[1024];
    __shared__ float red[4];
    __shared__ float4 ps[128];
    int b = blockIdx.x, p = blockIdx.y, tid = threadIdx.x;
    const float* sb = scores + b * T_;
    float v[4];
#pragma unroll
    for (int i = 0; i < 4; ++i) {
        int t = tid + i * 256;
        v[i] = (t < T_) ? sb[t] : -1e30f;
        sS[t] = v[i];
    }
    float mx = fmaxf(fmaxf(v[0], v[1]), fmaxf(v[2], v[3]));
#pragma unroll
    for (int off = 32; off >= 1; off >>= 1) mx = fmaxf(mx, __shfl_xor(mx, off));
    int wvi = tid >> 6, lane = tid & 63;
    if (lane == 0) red[wvi] = mx;
    __syncthreads();
    mx = fmaxf(fmaxf(red[0], red[1]), fmaxf(red[2], red[3]));
    float sum = 0.f;
#pragma unroll
    for (int i = 0; i < 4; ++i)
        sum += (tid + i * 256 < T_) ? __expf(v[i] - mx) : 0.f;
#pragma unroll
    for (int off = 32; off >= 1; off >>= 1) sum += __shfl_xor(sum, off);
    __syncthreads();
    if (lane == 0) red[wvi] = sum;
    __syncthreads();
    float inv = 1.0f / (red[0] + red[1] + red[2] + red[3]);

    int t0 = p * CT_;
    int len = (T_ - t0 < CT_) ? (T_ - t0) : CT_;
    if (tid < len) attw[b * T_ + t0 + tid] = __expf(sS[t0 + tid] - mx) * inv;

    int cl = tid & 127, tp = tid >> 7;
    const float* vp = values + ((size_t)b * T_ + t0) * DV_ + cl * 4;
    float4 a = {0.f, 0.f, 0.f, 0.f};
#pragma unroll 4
    for (int t = tp; t < len; t += 2) {
        float4 vv = *(const float4*)(vp + (size_t)t * DV_);
        float wt = __expf(sS[t0 + t] - mx) * inv;
        a.x += wt * vv.x; a.y += wt * vv.y; a.z += wt * vv.z; a.w += wt * vv.w;
    }
    if (tp == 1) ps[cl] = a;
    __syncthreads();
    if (tp == 0) {
        float4 o = ps[cl];
        o.x += a.x; o.y += a.y; o.z += a.z; o.w += a.w;
        *(float4*)(part + ((size_t)(b * P_ + p)) * DV_ + cl * 4) = o;
    }
}

// context phase 2: ctx[b,d] = sum_p partial[b,p,d]
__global__ void ctx2_kernel(const float* __restrict__ part, float* __restrict__ ctx) {
    int b = blockIdx.x, tid = threadIdx.x;   // 128 threads, float4 each
    const float* pp = part + (size_t)b * P_ * DV_ + tid * 4;
    float4 s = {0.f, 0.f, 0.f, 0.f};
#pragma unroll
    for (int p = 0; p < P_; ++p) {
        float4 v = *(const float4*)(pp + (size_t)p * DV_);
        s.x += v.x; s.y += v.y; s.z += v.z; s.w += v.w;
    }
    *(float4*)(ctx + (size_t)b * DV_ + tid * 4) = s;
}

extern "C" void kernel_launch(void* const* d_in, const int* in_sizes, int n_in,
                              void* d_out, int out_size, void* d_ws, size_t ws_size,
                              hipStream_t stream) {
    const float* query  = (const float*)d_in[0];
    const float* values = (const float*)d_in[1];
    const float* prev   = (const float*)d_in[2];
    const float* Wq     = (const float*)d_in[3];
    const float* bq     = (const float*)d_in[4];
    const float* Wm     = (const float*)d_in[5];
    const float* bm     = (const float*)d_in[6];
    const float* Wv     = (const float*)d_in[7];
    const float* bv     = (const float*)d_in[8];
    const float* Wc     = (const float*)d_in[9];
    const float* Wl     = (const float*)d_in[10];

    float* out  = (float*)d_out;
    float* ctx  = out;                 // [64,512]
    float* attw = out + B_ * DV_;      // [64,1000,1]

    char* ws = (char*)d_ws;
    float* qb     = (float*)(ws);                              // 32768 B
    float* scores = (float*)(ws + 32768);                      // 256000 B
    short* WmX    = (short*)(ws + 288768);                     // 131072 B
    short* WlX    = (short*)(ws + 419840);                     // 8192 B
    float* part   = (float*)(ws + 428032);                     // 2 MB

    prep_qb_kernel<<<73, 1024, 0, stream>>>(Wm, Wl, query, Wq, bq, bm, WmX, WlX, qb);
    score_kernel<<<1000, 256, 0, stream>>>(values, prev, Wc, Wv, bv, WmX, WlX, qb, scores);
    ctxsm_kernel<<<dim3(B_, P_), 256, 0, stream>>>(scores, values, attw, part);
    ctx2_kernel<<<B_, 128, 0, stream>>>(part, ctx);
}